// Round 9
// baseline (433.846 us; speedup 1.0000x reference)
//
#include <hip/hip_runtime.h>
#include <hip/hip_fp16.h>

#define BN_EPS 1e-5f
#define CHUNK 2048            // edges per bucketing block (hist and scatter must match)
#define BBITS 7               // 128 nodes per bucket

typedef _Float16 half8 __attribute__((ext_vector_type(8)));
typedef _Float16 half2v __attribute__((ext_vector_type(2)));
typedef float f32x4 __attribute__((ext_vector_type(4)));

__device__ __forceinline__ float4 f4zero() { return make_float4(0.f, 0.f, 0.f, 0.f); }

// ---------------- bucket-sort CSR build (no device-scope returning atomics) ----------------

__global__ __launch_bounds__(256) void k_bucket_hist(const int* __restrict__ dst,
                                                     int* __restrict__ tableT,
                                                     int nA, int nbuck, int e) {
    __shared__ int h[1024];
    int blk = blockIdx.x, tid = threadIdx.x;
    for (int k = tid; k < 1024; k += 256) h[k] = 0;
    __syncthreads();
    int base = blk * CHUNK;
    if (base + CHUNK <= e && (e & 3) == 0) {
        const int4* d4 = (const int4*)(dst + base);
#pragma unroll
        for (int t = 0; t < CHUNK / 1024; ++t) {
            int4 d = d4[t * 256 + tid];
            atomicAdd(&h[d.x >> BBITS], 1);
            atomicAdd(&h[d.y >> BBITS], 1);
            atomicAdd(&h[d.z >> BBITS], 1);
            atomicAdd(&h[d.w >> BBITS], 1);
        }
    } else {
        for (int i = base + tid; i < e && i < base + CHUNK; i += 256)
            atomicAdd(&h[dst[i] >> BBITS], 1);
    }
    __syncthreads();
    for (int k = tid; k < nbuck; k += 256)
        tableT[(size_t)k * nA + blk] = h[k];
}

__global__ __launch_bounds__(256) void k_bucket_scatter(const int* __restrict__ src,
                                                        const int* __restrict__ dst,
                                                        const int* __restrict__ tableT,
                                                        int2* __restrict__ bed,
                                                        int nA, int nbuck, int e) {
    __shared__ int cur[1024];
    int blk = blockIdx.x, tid = threadIdx.x;
    for (int k = tid; k < nbuck; k += 256)
        cur[k] = tableT[(size_t)k * nA + blk];
    __syncthreads();
    int base = blk * CHUNK;
    if (base + CHUNK <= e && (e & 3) == 0) {
        const int4* s4 = (const int4*)(src + base);
        const int4* d4 = (const int4*)(dst + base);
#pragma unroll
        for (int t = 0; t < CHUNK / 1024; ++t) {
            int4 s = s4[t * 256 + tid];
            int4 d = d4[t * 256 + tid];
            int p0 = atomicAdd(&cur[d.x >> BBITS], 1); bed[p0] = make_int2(s.x, d.x);
            int p1 = atomicAdd(&cur[d.y >> BBITS], 1); bed[p1] = make_int2(s.y, d.y);
            int p2 = atomicAdd(&cur[d.z >> BBITS], 1); bed[p2] = make_int2(s.z, d.z);
            int p3 = atomicAdd(&cur[d.w >> BBITS], 1); bed[p3] = make_int2(s.w, d.w);
        }
    } else {
        for (int i = base + tid; i < e && i < base + CHUNK; i += 256) {
            int d = dst[i];
            int p = atomicAdd(&cur[d >> BBITS], 1);
            bed[p] = make_int2(src[i], d);
        }
    }
}

// per-bucket rank + counts + dinv (dinv folded in; no global atomics anywhere)
__global__ __launch_bounds__(256) void k_bucket_rank(const int2* __restrict__ bed,
                                                     const int* __restrict__ tableT,
                                                     int* __restrict__ brank,
                                                     int* __restrict__ counts,
                                                     float* __restrict__ dinv,
                                                     int nA, int nbuck, int n, int e) {
    __shared__ int lcnt[128];
    int b = blockIdx.x, tid = threadIdx.x;
    if (tid < 128) lcnt[tid] = 0;
    __syncthreads();
    int start = tableT[(size_t)b * nA];
    int end = (b + 1 < nbuck) ? tableT[(size_t)(b + 1) * nA] : e;
    for (int i = start + tid; i < end; i += 256) {
        int2 q = bed[i];
        brank[i] = atomicAdd(&lcnt[q.y & ((1 << BBITS) - 1)], 1);
    }
    __syncthreads();
    if (tid < 128) {
        int node = (b << BBITS) + tid;
        if (node < n) {
            int c = lcnt[tid];
            counts[node] = c;
            dinv[node] = rsqrtf((float)(c + 1));
        }
    }
}

template <bool PAD8>
__global__ __launch_bounds__(1024) void k_scan_block(const int* __restrict__ counts,
                                                     int* __restrict__ offs,
                                                     int* __restrict__ partials, int len) {
    __shared__ int s[1024];
    int t = threadIdx.x;
    int gid = blockIdx.x * 1024 + t;
    int c = (gid < len) ? counts[gid] : 0;
    int v = PAD8 ? ((c + 7) & ~7) : c;
    int x = v;
    s[t] = x;
    __syncthreads();
    for (int d = 1; d < 1024; d <<= 1) {
        int y = (t >= d) ? s[t - d] : 0;
        __syncthreads();
        x += y;
        s[t] = x;
        __syncthreads();
    }
    if (gid < len) offs[gid] = x - v;
    if (t == 1023) partials[blockIdx.x] = x;
}

__global__ __launch_bounds__(1024) void k_scan_partials(int* __restrict__ partials, int nb) {
    __shared__ int s[1024];
    int t = threadIdx.x;
    int v = (t < nb) ? partials[t] : 0;
    int x = v;
    s[t] = x;
    __syncthreads();
    for (int d = 1; d < 1024; d <<= 1) {
        int y = (t >= d) ? s[t - d] : 0;
        __syncthreads();
        x += y;
        s[t] = x;
        __syncthreads();
    }
    if (t < nb) partials[t] = x - v;
    if (t == nb - 1) partials[nb] = x;
}

__global__ __launch_bounds__(256) void k_scan_add(int* __restrict__ offs,
                                                  const int* __restrict__ partials, int len) {
    int gid = blockIdx.x * 256 + threadIdx.x;
    if (gid < len) offs[gid] += partials[gid >> 10];
    if (gid == 0) offs[len] = partials[(len + 1023) >> 10];
}

__global__ __launch_bounds__(256) void k_fill(int4* __restrict__ er4, int val, int m4) {
    int i = blockIdx.x * 256 + threadIdx.x;
    if (i < m4) er4[i] = make_int4(val, val, val, val);
}

__global__ __launch_bounds__(256) void k_place2(const int2* __restrict__ bed,
                                                const int* __restrict__ brank,
                                                const int* __restrict__ offs,
                                                int* __restrict__ er, int e) {
    int i = (blockIdx.x * 256 + threadIdx.x) * 2;
    if (i + 1 < e) {
        int4 q = *(const int4*)(bed + i);
        int2 r = *(const int2*)(brank + i);
        er[offs[q.y] + r.x] = q.x;
        er[offs[q.w] + r.y] = q.z;
    } else if (i < e) {
        int2 q = bed[i];
        er[offs[q.y] + brank[i]] = q.x;
    }
}

// ---------------- W pre-pack: f32 [128][128] -> f16 B-fragment order ----------------

__global__ __launch_bounds__(256) void k_packW(const float* __restrict__ W,
                                               _Float16* __restrict__ out) {
    int t = blockIdx.x * 256 + threadIdx.x;
    if (t >= 2048) return;
    int kc = t >> 9;
    int rem = t & 511;
    int ct = rem >> 6;
    int lane = rem & 63;
    int q = lane >> 4;
    int col = ct * 16 + (lane & 15);
    half8 h;
#pragma unroll
    for (int j = 0; j < 8; ++j)
        h[j] = (_Float16)W[(kc * 32 + q * 8 + j) * 128 + col];
    *(half8*)(out + (size_t)t * 8) = h;
}

// ---------------- MFMA GEMM: C[n,128](f16) = (A @ W) * dinv[row] ----------------

template <bool AF32>
__global__ __launch_bounds__(256) void k_gemm_mfma(const void* __restrict__ Av,
                                                   const _Float16* __restrict__ pW,
                                                   const float* __restrict__ dinv,
                                                   uint4* __restrict__ C, int n) {
    __shared__ char smem[32768];
    uint4* sW = (uint4*)smem;
    int tid = threadIdx.x;

    {
        const uint4* gW = (const uint4*)pW;
#pragma unroll
        for (int i = 0; i < 8; ++i) sW[tid + 256 * i] = gW[tid + 256 * i];
    }
    __syncthreads();

    int wave = tid >> 6, lane = tid & 63;
    int quad = lane >> 4, l16 = lane & 15;
    int row0 = blockIdx.x * 64 + wave * 16;
    int arow = row0 + l16;
    int arowc = (arow < n) ? arow : (n - 1);

    half8 af[4];
    if (AF32) {
        const float* A = (const float*)Av + (size_t)arowc * 128 + quad * 8;
#pragma unroll
        for (int kc = 0; kc < 4; ++kc) {
            float4 lo = *(const float4*)(A + kc * 32);
            float4 hi = *(const float4*)(A + kc * 32 + 4);
            half8 h;
            h[0] = (_Float16)lo.x; h[1] = (_Float16)lo.y;
            h[2] = (_Float16)lo.z; h[3] = (_Float16)lo.w;
            h[4] = (_Float16)hi.x; h[5] = (_Float16)hi.y;
            h[6] = (_Float16)hi.z; h[7] = (_Float16)hi.w;
            af[kc] = h;
        }
    } else {
        const _Float16* A = (const _Float16*)Av + (size_t)arowc * 128 + quad * 8;
#pragma unroll
        for (int kc = 0; kc < 4; ++kc)
            af[kc] = *(const half8*)(A + kc * 32);
    }

    f32x4 acc[8];
#pragma unroll
    for (int ct = 0; ct < 8; ++ct) acc[ct] = (f32x4){0.f, 0.f, 0.f, 0.f};

#pragma unroll
    for (int kc = 0; kc < 4; ++kc) {
#pragma unroll
        for (int ct = 0; ct < 8; ++ct) {
            half8 bf = *(half8*)&sW[(kc * 8 + ct) * 64 + lane];
            acc[ct] = __builtin_amdgcn_mfma_f32_16x16x32_f16(af[kc], bf, acc[ct], 0, 0, 0);
        }
    }

    __syncthreads();

    _Float16* eb = (_Float16*)smem + wave * 16 * 136;
    float dv[4];
#pragma unroll
    for (int r = 0; r < 4; ++r) {
        int rr = row0 + quad * 4 + r;
        dv[r] = dinv[(rr < n) ? rr : (n - 1)];
    }
#pragma unroll
    for (int ct = 0; ct < 8; ++ct)
#pragma unroll
        for (int r = 0; r < 4; ++r)
            eb[(quad * 4 + r) * 136 + ct * 16 + l16] = (_Float16)(acc[ct][r] * dv[r]);

#pragma unroll
    for (int i = 0; i < 4; ++i) {
        int linear = i * 64 + lane;
        int r = linear >> 4, c = linear & 15;
        uint4 v = *(uint4*)((char*)eb + r * 272 + c * 16);
        int row = row0 + r;
        if (row < n) C[(size_t)row * 16 + c] = v;
    }
}

// ---------------- CSR aggregation + bias + ReLU + BN (+ optional classifier) ----------------
// 32 lanes per node; PAIRED-EDGE uint4 gathers (lanes 0-15 edge e, 16-31 edge e+1,
// 16 B/lane) halve vmem instructions; fdot2 basis-extract accumulation halves VALU.
// acc[j] is f32; combine halves once per node via shfl_xor(16).

__device__ __forceinline__ void accum8(float* acc, uint4 q) {
    const half2v b0 = {(_Float16)1.0f, (_Float16)0.0f};
    const half2v b1 = {(_Float16)0.0f, (_Float16)1.0f};
    unsigned int u[4] = {q.x, q.y, q.z, q.w};
#pragma unroll
    for (int k = 0; k < 4; ++k) {
        half2v h = *(half2v*)&u[k];
        acc[2 * k + 0] = __builtin_amdgcn_fdot2(h, b0, acc[2 * k + 0], false);
        acc[2 * k + 1] = __builtin_amdgcn_fdot2(h, b1, acc[2 * k + 1], false);
    }
}

template <bool FUSE_CLS>
__global__ __launch_bounds__(256) void k_aggregate(const uint4* __restrict__ Ah4,
                                                   const int* __restrict__ offs,
                                                   const int* __restrict__ er,
                                                   const float* __restrict__ dinv,
                                                   const float* __restrict__ bias,
                                                   const float* __restrict__ g,
                                                   const float* __restrict__ be,
                                                   const float* __restrict__ rm,
                                                   const float* __restrict__ rv,
                                                   uint4* __restrict__ Hout,
                                                   const float* __restrict__ Wc,
                                                   const float* __restrict__ bc,
                                                   float* __restrict__ out, int n) {
    int lane32 = threadIdx.x & 31;
    int node = blockIdx.x * 8 + (threadIdx.x >> 5);
    if (node >= n) return;
    int sub = lane32 & 15;          // feature block: features sub*8 .. sub*8+7
    bool hi = lane32 >= 16;         // odd-edge half-group

    float acc[8];
#pragma unroll
    for (int j = 0; j < 8; ++j) acc[j] = 0.f;

    {   // self row (once: lo half only)
        uint4 qs = Ah4[(size_t)node * 16 + sub];
        if (!hi) accum8(acc, qs);
    }

    int e0 = offs[node], e1 = offs[node + 1];
    for (int e = e0; e < e1; e += 8) {
        int4 ra = *(const int4*)(er + e);
        int4 rb = *(const int4*)(er + e + 4);
        int r0 = hi ? ra.y : ra.x;
        int r1 = hi ? ra.w : ra.z;
        int r2 = hi ? rb.y : rb.x;
        int r3 = hi ? rb.w : rb.z;
        uint4 q0 = Ah4[(size_t)r0 * 16 + sub];
        uint4 q1 = Ah4[(size_t)r1 * 16 + sub];
        uint4 q2 = Ah4[(size_t)r2 * 16 + sub];
        uint4 q3 = Ah4[(size_t)r3 * 16 + sub];
        accum8(acc, q0); accum8(acc, q1); accum8(acc, q2); accum8(acc, q3);
    }

#pragma unroll
    for (int j = 0; j < 8; ++j) acc[j] += __shfl_xor(acc[j], 16, 32);

    float di = dinv[node];
    const float4* b4 = (const float4*)bias;
    const float4* g4 = (const float4*)g;
    const float4* be4 = (const float4*)be;
    const float4* rm4 = (const float4*)rm;
    const float4* rv4 = (const float4*)rv;

    float o[8];
#pragma unroll
    for (int h = 0; h < 2; ++h) {
        float4 bb = b4[sub * 2 + h], gg = g4[sub * 2 + h], ee = be4[sub * 2 + h];
        float4 mm = rm4[sub * 2 + h], vv = rv4[sub * 2 + h];
        float v;
        v = fmaxf(acc[4 * h + 0] * di + bb.x, 0.f); o[4 * h + 0] = (v - mm.x) * rsqrtf(vv.x + BN_EPS) * gg.x + ee.x;
        v = fmaxf(acc[4 * h + 1] * di + bb.y, 0.f); o[4 * h + 1] = (v - mm.y) * rsqrtf(vv.y + BN_EPS) * gg.y + ee.y;
        v = fmaxf(acc[4 * h + 2] * di + bb.z, 0.f); o[4 * h + 2] = (v - mm.z) * rsqrtf(vv.z + BN_EPS) * gg.z + ee.z;
        v = fmaxf(acc[4 * h + 3] * di + bb.w, 0.f); o[4 * h + 3] = (v - mm.w) * rsqrtf(vv.w + BN_EPS) * gg.w + ee.w;
    }

    if (!FUSE_CLS) {
        if (!hi) {
            __half2 p0 = __floats2half2_rn(o[0], o[1]);
            __half2 p1 = __floats2half2_rn(o[2], o[3]);
            __half2 p2 = __floats2half2_rn(o[4], o[5]);
            __half2 p3 = __floats2half2_rn(o[6], o[7]);
            uint4 u;
            u.x = *(unsigned int*)&p0; u.y = *(unsigned int*)&p1;
            u.z = *(unsigned int*)&p2; u.w = *(unsigned int*)&p3;
            Hout[(size_t)node * 16 + sub] = u;
        }
    } else {
        const float4* Wv = (const float4*)Wc;    // [128][2] row-major
        float p0 = 0.f, p1 = 0.f;
#pragma unroll
        for (int k = 0; k < 4; ++k) {
            float4 w = Wv[sub * 4 + k];          // rows sub*8+2k, sub*8+2k+1
            p0 += o[2 * k] * w.x + o[2 * k + 1] * w.z;
            p1 += o[2 * k] * w.y + o[2 * k + 1] * w.w;
        }
#pragma unroll
        for (int d = 8; d >= 1; d >>= 1) {
            p0 += __shfl_down(p0, d, 16);
            p1 += __shfl_down(p1, d, 16);
        }
        if (lane32 == 0) {
            out[node * 2 + 0] = p0 + bc[0];
            out[node * 2 + 1] = p1 + bc[1];
        }
    }
}

// ---------------- launch ----------------

extern "C" void kernel_launch(void* const* d_in, const int* in_sizes, int n_in,
                              void* d_out, int out_size, void* d_ws, size_t ws_size,
                              hipStream_t stream) {
    const float* x   = (const float*)d_in[0];
    const int*   ei  = (const int*)d_in[1];
    const float* W1  = (const float*)d_in[2];
    const float* b1  = (const float*)d_in[3];
    const float* W2  = (const float*)d_in[4];
    const float* b2  = (const float*)d_in[5];
    const float* W3  = (const float*)d_in[6];
    const float* b3  = (const float*)d_in[7];
    const float* g1  = (const float*)d_in[8];
    const float* be1 = (const float*)d_in[9];
    const float* rm1 = (const float*)d_in[10];
    const float* rv1 = (const float*)d_in[11];
    const float* g2  = (const float*)d_in[12];
    const float* be2 = (const float*)d_in[13];
    const float* rm2 = (const float*)d_in[14];
    const float* rv2 = (const float*)d_in[15];
    const float* g3  = (const float*)d_in[16];
    const float* be3 = (const float*)d_in[17];
    const float* rm3 = (const float*)d_in[18];
    const float* rv3 = (const float*)d_in[19];
    const float* Wc  = (const float*)d_in[20];
    const float* bc  = (const float*)d_in[21];
    float* out = (float*)d_out;

    int n = in_sizes[0] / 128;
    int e = in_sizes[1] / 2;
    const int* src = ei;
    const int* dst = ei + e;

    char* ws = (char*)d_ws;
    size_t off = 0;
    auto alloc = [&](size_t bytes) -> char* {
        char* p = ws + off;
        off += (bytes + 255) & ~(size_t)255;
        return p;
    };
    int erCap = e + 8 * n;
    uint2*     bufA   = (uint2*)alloc((size_t)(n + 1) * 128 * 2);
    char*      bufH   = (char*) alloc((size_t)n * 128 * 4);
    float*     dinv   = (float*)alloc((size_t)n * 4);
    int*       counts = (int*)  alloc((size_t)n * 4);
    int*       offs   = (int*)  alloc((size_t)(n + 1) * 4);
    int*       parts  = (int*)  alloc(8192);
    int*       er     = (int*)  alloc((size_t)erCap * 4);
    _Float16*  pW     = (_Float16*)alloc(3 * 16384 * 2);
    (void)ws_size; (void)n_in; (void)out_size;

    int nA    = (e + CHUNK - 1) / CHUNK;
    int nbuck = (n + (1 << BBITS) - 1) >> BBITS;
    int tlen  = nbuck * nA;
    {
        char* p = bufH + (size_t)n * 128 * 2;
        size_t po = 0;
        auto palloc = [&](size_t bytes) -> char* {
            char* q = p + po;
            po += (bytes + 255) & ~(size_t)255;
            return q;
        };
        // scratch: e*8 + e*4 + tlen*4 = 12.8 + 6.4 + 2.5 MB < 25.6 MB available
        int2* bed    = (int2*)palloc((size_t)e * 8);
        int*  brank  = (int*) palloc((size_t)e * 4);
        int*  tableT = (int*) palloc((size_t)(tlen + 1) * 4);

        hipMemsetAsync(bufA + (size_t)n * 32, 0, 256, stream);

        int gN  = (n + 255) / 256;
        int nb  = (n + 1023) / 1024;
        int nbT = (tlen + 1023) / 1024;
        int m4  = erCap / 4;

        k_packW<<<8, 256, 0, stream>>>(W1, pW);
        k_packW<<<8, 256, 0, stream>>>(W2, pW + 16384);
        k_packW<<<8, 256, 0, stream>>>(W3, pW + 32768);
        k_bucket_hist<<<nA, 256, 0, stream>>>(dst, tableT, nA, nbuck, e);
        k_scan_block<false><<<nbT, 1024, 0, stream>>>(tableT, tableT, parts, tlen);
        k_scan_partials<<<1, 1024, 0, stream>>>(parts, nbT);
        k_scan_add<<<(tlen + 255) / 256, 256, 0, stream>>>(tableT, parts, tlen);
        k_bucket_scatter<<<nA, 256, 0, stream>>>(src, dst, tableT, bed, nA, nbuck, e);
        k_bucket_rank<<<nbuck, 256, 0, stream>>>(bed, tableT, brank, counts, dinv, nA, nbuck, n, e);
        k_scan_block<true><<<nb, 1024, 0, stream>>>(counts, offs, parts, n);
        k_scan_partials<<<1, 1024, 0, stream>>>(parts, nb);
        k_scan_add<<<gN, 256, 0, stream>>>(offs, parts, n);
        k_fill<<<(m4 + 255) / 256, 256, 0, stream>>>((int4*)er, n, m4);
        k_place2<<<((e + 1) / 2 + 255) / 256, 256, 0, stream>>>(bed, brank, offs, er, e);
    }

    int gGemm = (n + 63) / 64;
    int gAgg  = (n + 7) / 8;

    k_gemm_mfma<true><<<gGemm, 256, 0, stream>>>(x, pW, dinv, (uint4*)bufA, n);
    k_aggregate<false><<<gAgg, 256, 0, stream>>>((const uint4*)bufA, offs, er, dinv,
                                                 b1, g1, be1, rm1, rv1, (uint4*)bufH,
                                                 nullptr, nullptr, nullptr, n);

    k_gemm_mfma<false><<<gGemm, 256, 0, stream>>>(bufH, pW + 16384, dinv, (uint4*)bufA, n);
    k_aggregate<false><<<gAgg, 256, 0, stream>>>((const uint4*)bufA, offs, er, dinv,
                                                 b2, g2, be2, rm2, rv2, (uint4*)bufH,
                                                 nullptr, nullptr, nullptr, n);

    k_gemm_mfma<false><<<gGemm, 256, 0, stream>>>(bufH, pW + 32768, dinv, (uint4*)bufA, n);
    k_aggregate<true><<<gAgg, 256, 0, stream>>>((const uint4*)bufA, offs, er, dinv,
                                                b3, g3, be3, rm3, rv3, nullptr,
                                                Wc, bc, out, n);
}